// Round 17
// baseline (138.579 us; speedup 1.0000x reference)
//
#include <hip/hip_runtime.h>
#include <hip/hip_bf16.h>

#define B_ 8
#define S_ 1024
#define E_ 256
#define H_ 8
#define HD_ 32
#define SCALE_ 0.17677669529663687f   // 32^-0.5
#define LOG2E_ 1.44269504088896f
#define QSCALE_ (SCALE_ * LOG2E_)
#define EPS_ 1e-5f

typedef __attribute__((ext_vector_type(8))) short bf16x8;
typedef __attribute__((ext_vector_type(4))) short bf16x4;
typedef __attribute__((ext_vector_type(4))) float f32x4;

__device__ inline short f2bf(float f) {
    union { float f; unsigned u; } v; v.f = f;
    unsigned r = v.u + 0x7fff + ((v.u >> 16) & 1);
    return (short)(r >> 16);
}

// single-instruction 2xf32 -> packed bf16x2 (RTNE) — gfx950 v_cvt_pk_bf16_f32
__device__ inline unsigned cvtpk(float a, float b) {
    unsigned r;
    asm("v_cvt_pk_bf16_f32 %0, %1, %2" : "=v"(r) : "v"(a), "v"(b));
    return r;
}

__device__ inline float fexp2(float x) {
#if __has_builtin(__builtin_amdgcn_exp2f)
    return __builtin_amdgcn_exp2f(x);
#else
    return exp2f(x);
#endif
}

__device__ inline float bf2f(unsigned short s) {
    return __uint_as_float((unsigned)s << 16);
}

// XOR-swizzled LDS byte offset for a [64][256] bf16 tile (512B rows).
__device__ inline int swz(int row, int kbyte) {
    return row * 512 + (kbyte ^ ((row & 7) << 4));
}

// ---------------------------------------------------------------------------
// Kernel 0: one-shot conversions (weights + pde only; x converted in k_qkv).
//  wib [768][256]     bf16   <- in_proj_w
//  wob [256][256]     bf16   <- out_w
//  pdef[sb][tb][lane][4] f32 <- pde * log2e, fragment-ordered:
//        lane = ((t>>2)&3)*16 + (s&15), r = t&3
// ---------------------------------------------------------------------------
__global__ __launch_bounds__(256) void k_prep(
    const float* __restrict__ wi, const float* __restrict__ wo,
    const float* __restrict__ pde,
    short* __restrict__ wib, short* __restrict__ wob,
    float* __restrict__ pdef)
{
    const int NWI = 768 * 256 / 4;        // 49152
    const int NWO = 256 * 256 / 4;        // 16384
    const int NP  = 1024 * 1024 / 4;      // 262144
    const int total = NWI + NWO + NP;
    for (int q4 = blockIdx.x * 256 + threadIdx.x; q4 < total;
         q4 += gridDim.x * 256) {
        if (q4 < NWI) {
            long i = (long)q4 * 4;
            float4 v = *reinterpret_cast<const float4*>(wi + i);
            short4 s; s.x = f2bf(v.x); s.y = f2bf(v.y); s.z = f2bf(v.z); s.w = f2bf(v.w);
            *reinterpret_cast<short4*>(wib + i) = s;
        } else if (q4 < NWI + NWO) {
            long i = (long)(q4 - NWI) * 4;
            float4 v = *reinterpret_cast<const float4*>(wo + i);
            short4 s; s.x = f2bf(v.x); s.y = f2bf(v.y); s.z = f2bf(v.z); s.w = f2bf(v.w);
            *reinterpret_cast<short4*>(wob + i) = s;
        } else {
            long i = (long)(q4 - NWI - NWO) * 4;
            int s = (int)(i >> 10), t = (int)(i & 1023);
            float4 v = *reinterpret_cast<const float4*>(pde + i);
            int dest = (s >> 4) * 16384 + (t >> 4) * 256
                     + ((((t >> 2) & 3) << 4) | (s & 15)) * 4;
            float4* d = reinterpret_cast<float4*>(pdef + dest);
            float4 o; o.x = v.x * LOG2E_; o.y = v.y * LOG2E_;
            o.z = v.z * LOG2E_; o.w = v.w * LOG2E_;
            *d = o;
        }
    }
}

// ---------------------------------------------------------------------------
// Kernel 1: QKV projection.  qkv = x @ Wi^T + bi  (M=8192/input, N=768, K=256)
// A staged ONCE from f32 x (f2bf in staging); each block computes FOUR
// consecutive n-tiles (grid.y = 3) -> sect == blockIdx.y is block-uniform.
// Outputs fragment-ordered per (inp,b,h) group g (64KB each). Epilogue per
// n-tile via LDS Tb[64][72].
// ---------------------------------------------------------------------------
__global__ __launch_bounds__(256) void k_qkv(
    const float* __restrict__ x0, const float* __restrict__ x1,
    const short* __restrict__ wib, const float* __restrict__ bias,
    short* __restrict__ qws, short* __restrict__ kws, short* __restrict__ vws)
{
    __shared__ alignas(16) short lA[64 * 256];
    __shared__ alignas(16) short lB[64 * 256];
    __shared__ alignas(16) short Tb[64 * 72];
    const int m0 = blockIdx.x * 64;
    const int inp = blockIdx.z;
    const float* x = inp ? x1 : x0;
    const int tid = threadIdx.x;

    // ---- stage A once (f32 x -> bf16 swizzled LDS) ----
    #pragma unroll
    for (int i = 0; i < 16; ++i) {
        int fid = tid + 256 * i;
        int r = fid >> 6, c4 = fid & 63;
        float4 vv = *reinterpret_cast<const float4*>(x + (long)(m0 + r) * 256 + c4 * 4);
        short4 sv; sv.x = f2bf(vv.x); sv.y = f2bf(vv.y); sv.z = f2bf(vv.z); sv.w = f2bf(vv.w);
        *reinterpret_cast<short4*>(reinterpret_cast<char*>(lA) + swz(r, c4 * 8)) = sv;
    }

    const int wv = tid >> 6, ln = tid & 63;
    const int row16 = ln & 15, kg = ln >> 4;
    const int arow = wv * 16 + row16;
    const int b = m0 >> 10;
    const int sbb = (m0 & 1023) >> 4;         // base 16-row tile index
    const int sect = blockIdx.y;              // 0=q 1=k 2=v (uniform)

    for (int t = 0; t < 4; ++t) {
        const int n0 = (blockIdx.y * 4 + t) * 64;

        // ---- stage B for this n-tile ----
        #pragma unroll
        for (int i = 0; i < 8; ++i) {
            int fid = tid + 256 * i;
            int r = fid >> 5, c = fid & 31;
            int4 v = *reinterpret_cast<const int4*>(wib + (long)(n0 + r) * 256 + c * 8);
            *reinterpret_cast<int4*>(reinterpret_cast<char*>(lB) + swz(r, c * 16)) = v;
        }
        __syncthreads();    // A+B visible; also orders prev emit before Tb rewrite

        f32x4 acc[4] = {};
        #pragma unroll
        for (int kc = 0; kc < 8; ++kc) {
            int kbyte = kc * 64 + kg * 16;
            bf16x8 af = *reinterpret_cast<const bf16x8*>(
                reinterpret_cast<char*>(lA) + swz(arow, kbyte));
            #pragma unroll
            for (int n = 0; n < 4; ++n) {
                int brow = n * 16 + row16;
                bf16x8 bfg = *reinterpret_cast<const bf16x8*>(
                    reinterpret_cast<char*>(lB) + swz(brow, kbyte));
                acc[n] = __builtin_amdgcn_mfma_f32_16x16x32_bf16(af, bfg, acc[n], 0, 0, 0);
            }
        }

        // ---- epilogue: stage tile in Tb (bf16), then coalesced emit ----
        #pragma unroll
        for (int n = 0; n < 4; ++n) {
            int o = n0 + n * 16 + row16;
            float bval = bias[o];
            #pragma unroll
            for (int r = 0; r < 4; ++r) {
                float val = acc[n][r] + bval;
                if (sect == 0) val *= QSCALE_;
                Tb[(wv * 16 + kg * 4 + r) * 72 + n * 16 + row16] = f2bf(val);
            }
        }
        __syncthreads();

        const int h0 = (n0 & 255) >> 5;       // base head (even)
        const long gi0 = (long)(inp * 64 + b * 8 + h0) * 32768;

        if (sect < 2) {
            short* dst = (sect == 0) ? qws : kws;
            #pragma unroll
            for (int i = 0; i < 2; ++i) {
                int uid = tid * 2 + i;        // 0..511
                int u = uid & 15;             // s16
                int chunk = uid >> 4;         // 0..31
                int oct = chunk & 3;
                int sb_loc = (chunk >> 2) & 3;
                int hh = chunk >> 4;          // 0..1
                int4 vv = *reinterpret_cast<const int4*>(
                    &Tb[(sb_loc * 16 + u) * 72 + hh * 32 + oct * 8]);
                long gi = gi0 + (long)hh * 32768;
                *reinterpret_cast<int4*>(
                    &dst[gi + (sbb + sb_loc) * 512 + oct * 128 + u * 8]) = vv;
            }
        } else {
            #pragma unroll
            for (int i = 0; i < 2; ++i) {
                int uid = tid * 2 + i;        // 0..511
                int u8 = uid & 7;             // unit within 64-short chunk
                int chunk = uid >> 3;         // 0..63
                int q4 = chunk & 3;
                int c = (chunk >> 2) & 1;
                int tb_loc = (chunk >> 3) & 3;
                int hh = chunk >> 5;          // 0..1
                int srow = tb_loc * 16 + q4 * 4;
                int col = hh * 32 + c * 16 + u8 * 2;
                unsigned p0 = *reinterpret_cast<const unsigned*>(&Tb[(srow + 0) * 72 + col]);
                unsigned p1 = *reinterpret_cast<const unsigned*>(&Tb[(srow + 1) * 72 + col]);
                unsigned p2 = *reinterpret_cast<const unsigned*>(&Tb[(srow + 2) * 72 + col]);
                unsigned p3 = *reinterpret_cast<const unsigned*>(&Tb[(srow + 3) * 72 + col]);
                int4 vv;
                vv.x = (int)((p0 & 0xffffu) | (p1 << 16));
                vv.y = (int)((p2 & 0xffffu) | (p3 << 16));
                vv.z = (int)((p0 >> 16) | (p1 & 0xffff0000u));
                vv.w = (int)((p2 >> 16) | (p3 & 0xffff0000u));
                long gi = gi0 + (long)hh * 32768;
                *reinterpret_cast<int4*>(
                    &vws[gi + (sbb + tb_loc) * 512 + c * 256 + q4 * 64 + u8 * 8]) = vv;
            }
        }
    }
}

// ---------------------------------------------------------------------------
// Kernel 2: flash attention, no online max. Swapped QK^T (A=K, B=Q, C=pdef
// f32 frag) -> lane owns q=lane&15, t=kg*4+r == A-frag of mfma 16x16x16, so
// PV consumes exp2'd scores with zero movement. Row-sum via a ones-MFMA into
// accs (same C layout as O accumulator -> denominator in-lane, no shfl).
// P pack via single-instruction v_cvt_pk_bf16_f32; exp via raw v_exp_f32.
// All loads fragment-ordered 1-segment. No LDS.  [byte-identical to R11]
// ---------------------------------------------------------------------------
__global__ __launch_bounds__(256) void k_attn(
    const short* __restrict__ qws, const short* __restrict__ kws,
    const short* __restrict__ vws, const float* __restrict__ pdef,
    short* __restrict__ aout)
{
    const int L = blockIdx.x;
    const int xcd = L & 7, kidx = L >> 3;
    const int qb = kidx >> 4;                 // 0..15
    const int g  = xcd * 16 + (kidx & 15);    // 0..127 = inp*64 + b*8 + h
    const int inp = g >> 6, bh = g & 63, b = bh >> 3, h = bh & 7;
    const int tid = threadIdx.x, wv = tid >> 6, ln = tid & 63;
    const int row16 = ln & 15, kg = ln >> 4;
    const long gbase = (long)g * 32768;
    const int sb = qb * 4 + wv;               // 16-row q-tile index (0..63)

    bf16x8 qf = *reinterpret_cast<const bf16x8*>(qws + gbase + sb * 512 + ln * 8);
    const short* kp = kws + gbase + ln * 8;
    const short* vp = vws + gbase + ln * 4;
    const float* pp = pdef + (long)sb * 16384 + ln * 4;

    union { unsigned u[2]; bf16x4 v; } ones;
    ones.u[0] = 0x3F803F80u; ones.u[1] = 0x3F803F80u;

    f32x4 acc0 = {}, acc1 = {}, accs = {};

    #pragma unroll 4
    for (int tb = 0; tb < 64; ++tb) {
        bf16x8 kf = *reinterpret_cast<const bf16x8*>(kp + tb * 512);
        f32x4 c = *reinterpret_cast<const f32x4*>(pp + tb * 256);
        f32x4 sv = __builtin_amdgcn_mfma_f32_16x16x32_bf16(kf, qf, c, 0, 0, 0);
        float p0 = fexp2(sv[0]), p1 = fexp2(sv[1]);
        float p2 = fexp2(sv[2]), p3 = fexp2(sv[3]);
        union { unsigned u[2]; bf16x4 v; } pa;
        pa.u[0] = cvtpk(p0, p1);
        pa.u[1] = cvtpk(p2, p3);
        bf16x4 v0 = *reinterpret_cast<const bf16x4*>(vp + tb * 512);
        bf16x4 v1 = *reinterpret_cast<const bf16x4*>(vp + tb * 512 + 256);
        acc0 = __builtin_amdgcn_mfma_f32_16x16x16bf16_1k(pa.v, v0, acc0, 0, 0, 0);
        acc1 = __builtin_amdgcn_mfma_f32_16x16x16bf16_1k(pa.v, v1, acc1, 0, 0, 0);
        accs = __builtin_amdgcn_mfma_f32_16x16x16bf16_1k(pa.v, ones.v, accs, 0, 0, 0);
    }

    // acc layout: O[q = kg*4+r][e = h*32 + c2*16 + row16]; accs[r] = rowsum(q)
    #pragma unroll
    for (int c2 = 0; c2 < 2; ++c2) {
        int e = h * 32 + c2 * 16 + row16;
        #pragma unroll
        for (int r = 0; r < 4; ++r) {
            int s = qb * 64 + wv * 16 + kg * 4 + r;
            float val = (c2 ? acc1[r] : acc0[r]) / accs[r];
            aout[((long)inp * 8192 + b * 1024 + s) * 256 + e] = f2bf(val);
        }
    }
}

// ---------------------------------------------------------------------------
// Kernel 3: out-proj GEMM + BN/MMD statistics.  Ya = a @ Wo^T + bo
// A-tile staged ONCE; each block computes TWO n-tiles (grid.y = 2).
// Writes Ya as bf16 into ws (yab); statistics accumulate from unrounded f32.
// ---------------------------------------------------------------------------
__global__ __launch_bounds__(256) void k_outproj(
    const short* __restrict__ a, const short* __restrict__ wob,
    const float* __restrict__ bias, short* __restrict__ yab,
    float* __restrict__ chsum, float* __restrict__ chsq,
    float* __restrict__ bsum)
{
    __shared__ alignas(16) short lA[64 * 256];
    __shared__ alignas(16) short lB[64 * 256];
    const int m0 = blockIdx.x * 64;
    const int inp = blockIdx.z;
    const int tid = threadIdx.x;
    const short* asrc = a + (long)inp * 8192 * 256;

    #pragma unroll
    for (int i = 0; i < 8; ++i) {
        int fid = tid + 256 * i;
        int r = fid >> 5, c = fid & 31;
        int4 v = *reinterpret_cast<const int4*>(asrc + (long)(m0 + r) * 256 + c * 8);
        *reinterpret_cast<int4*>(reinterpret_cast<char*>(lA) + swz(r, c * 16)) = v;
    }

    const int wv = tid >> 6, ln = tid & 63;
    const int row16 = ln & 15, kg = ln >> 4;
    const int arow = wv * 16 + row16;

    for (int t = 0; t < 2; ++t) {
        const int n0 = (blockIdx.y * 2 + t) * 64;
        #pragma unroll
        for (int i = 0; i < 8; ++i) {
            int fid = tid + 256 * i;
            int r = fid >> 5, c = fid & 31;
            int4 v = *reinterpret_cast<const int4*>(wob + (long)(n0 + r) * 256 + c * 8);
            *reinterpret_cast<int4*>(reinterpret_cast<char*>(lB) + swz(r, c * 16)) = v;
        }
        __syncthreads();    // A+B visible

        f32x4 acc[4] = {};
        #pragma unroll
        for (int kc = 0; kc < 8; ++kc) {
            int kbyte = kc * 64 + kg * 16;
            bf16x8 af = *reinterpret_cast<const bf16x8*>(
                reinterpret_cast<char*>(lA) + swz(arow, kbyte));
            #pragma unroll
            for (int n = 0; n < 4; ++n) {
                int brow = n * 16 + row16;
                bf16x8 bfg = *reinterpret_cast<const bf16x8*>(
                    reinterpret_cast<char*>(lB) + swz(brow, kbyte));
                acc[n] = __builtin_amdgcn_mfma_f32_16x16x32_bf16(af, bfg, acc[n], 0, 0, 0);
            }
        }
        #pragma unroll
        for (int n = 0; n < 4; ++n) {
            int o = n0 + n * 16 + row16;
            float bv = bias[o];
            float sum = 0.f, sq = 0.f;
            #pragma unroll
            for (int r = 0; r < 4; ++r) {
                long grow = m0 + wv * 16 + kg * 4 + r;
                float val = acc[n][r] + bv;
                yab[(long)inp * 2097152 + grow * 256 + o] = f2bf(val);
                sum += val; sq += val * val;
            }
            sum += __shfl_xor(sum, 16); sum += __shfl_xor(sum, 32);
            sq  += __shfl_xor(sq, 16);  sq  += __shfl_xor(sq, 32);
            if (kg == 0) {
                atomicAdd(&chsum[inp * 256 + o], sum);
                atomicAdd(&chsq[inp * 256 + o], sq);
                int b = m0 >> 10;
                atomicAdd(&bsum[(inp * 8 + b) * 256 + o], sum);
            }
        }
        __syncthreads();    // ensure MFMA reads of lB done before restage
    }
}

// ---------------------------------------------------------------------------
// Kernel 4 (1 block): BN stats -> affine params; per-(b,e) means -> MMD loss.
// Distance loop vectorized: tot stride 276 floats (16B-aligned rows) +
// float4 LDS reads (64 iters instead of 256 scalar).
// ---------------------------------------------------------------------------
__global__ __launch_bounds__(256) void k_finalize(
    const float* __restrict__ chsum, const float* __restrict__ chsq,
    const float* __restrict__ bsum, const float* __restrict__ gamma,
    const float* __restrict__ beta, const float* __restrict__ gamma2,
    const float* __restrict__ beta2, const float* __restrict__ bnw,
    float* __restrict__ params, float* __restrict__ loss_out)
{
    __shared__ float tot[16][276];
    __shared__ float red[8];
    const int tid = threadIdx.x;
    const float w = (1.f / (1.f + __expf(-bnw[0])) + 1.f) * 0.5f;
    const int e = tid;
    float m1 = chsum[e] * (1.f / 8192.f);
    float v1 = chsq[e] * (1.f / 8192.f) - m1 * m1;
    float m2 = chsum[256 + e] * (1.f / 8192.f);
    float v2 = chsq[256 + e] * (1.f / 8192.f) - m2 * m2;
    float mfa = w * m1 + (1.f - w) * m2, mfb = w * m2 + (1.f - w) * m1;
    float vfa = w * v1 + (1.f - w) * v2, vfb = w * v2 + (1.f - w) * v1;
    float sA = gamma[e] * rsqrtf(vfa + EPS_);
    float bA = beta[e] - sA * mfa;
    float sB = gamma2[e] * rsqrtf(vfb + EPS_);
    float bB = beta2[e] - sB * mfb;
    params[e] = sA; params[256 + e] = bA; params[512 + e] = sB; params[768 + e] = bB;
    #pragma unroll
    for (int b = 0; b < 8; ++b) {
        tot[b][e]     = sA * (bsum[b * 256 + e] * (1.f / 1024.f)) + bA;
        tot[8 + b][e] = sB * (bsum[(8 + b) * 256 + e] * (1.f / 1024.f)) + bB;
    }
    __syncthreads();
    const int i = tid >> 4, j = tid & 15;
    const float4* ri = reinterpret_cast<const float4*>(&tot[i][0]);
    const float4* rj = reinterpret_cast<const float4*>(&tot[j][0]);
    float d = 0.f;
    for (int ee = 0; ee < 64; ++ee) {
        float4 va = ri[ee], vb = rj[ee];
        float dx = va.x - vb.x, dy = va.y - vb.y;
        float dz = va.z - vb.z, dw = va.w - vb.w;
        d += (dx * dx + dy * dy) + (dz * dz + dw * dw);
    }
    float t = d;
    #pragma unroll
    for (int off = 1; off < 64; off <<= 1) t += __shfl_xor(t, off);
    if ((tid & 63) == 0) red[tid >> 6] = t;
    __syncthreads();
    float dsum = red[0] + red[1] + red[2] + red[3];
    float bw = dsum * (1.f / 240.f) * 0.25f;
    float kern = 0.f, bwi = bw;
    #pragma unroll
    for (int kkk = 0; kkk < 5; ++kkk) { kern += __expf(-d / bwi); bwi *= 2.f; }
    float c = (((i < 8) == (j < 8)) ? 1.f : -1.f) * kern;
    #pragma unroll
    for (int off = 1; off < 64; off <<= 1) c += __shfl_xor(c, off);
    if ((tid & 63) == 0) red[4 + (tid >> 6)] = c;
    __syncthreads();
    if (tid == 0) loss_out[0] = (red[4] + red[5] + red[6] + red[7]) * (1.f / 64.f);
}

// ---------------------------------------------------------------------------
// Kernel 5: affine from bf16 Ya -> f32 d_out (Y = sA*Ya + bA, Y2 = sB*Yb + bB)
// params staged in LDS once per block.
// ---------------------------------------------------------------------------
__global__ __launch_bounds__(256) void k_affine(
    const short* __restrict__ yab, float* __restrict__ y,
    const float* __restrict__ params)
{
    __shared__ float pl[1024];
    {
        float4 v = *reinterpret_cast<const float4*>(params + threadIdx.x * 4);
        *reinterpret_cast<float4*>(pl + threadIdx.x * 4) = v;
    }
    __syncthreads();
    const long total4 = 4194304 / 4;
    for (long idx4 = (long)blockIdx.x * 256 + threadIdx.x; idx4 < total4;
         idx4 += (long)gridDim.x * 256) {
        long idx = idx4 * 4;
        int inp = (int)((idx >> 21) & 1);
        int e = (int)(idx & 255);
        const float* sA = pl + inp * 512;
        const float* bA = sA + 256;
        short4 s = *reinterpret_cast<const short4*>(yab + idx);
        float4 v;
        v.x = bf2f((unsigned short)s.x);
        v.y = bf2f((unsigned short)s.y);
        v.z = bf2f((unsigned short)s.z);
        v.w = bf2f((unsigned short)s.w);
        v.x = sA[e] * v.x + bA[e];
        v.y = sA[e + 1] * v.y + bA[e + 1];
        v.z = sA[e + 2] * v.z + bA[e + 2];
        v.w = sA[e + 3] * v.w + bA[e + 3];
        *reinterpret_cast<float4*>(y + idx) = v;
    }
}

extern "C" void kernel_launch(void* const* d_in, const int* in_sizes, int n_in,
                              void* d_out, int out_size, void* d_ws, size_t ws_size,
                              hipStream_t stream) {
    (void)in_sizes; (void)n_in; (void)out_size; (void)ws_size;
    const float* x    = (const float*)d_in[0];
    const float* x2   = (const float*)d_in[1];
    const float* pde  = (const float*)d_in[2];
    const float* wi   = (const float*)d_in[3];
    const float* bi   = (const float*)d_in[4];
    const float* wo   = (const float*)d_in[5];
    const float* bo   = (const float*)d_in[6];
    const float* gam  = (const float*)d_in[7];
    const float* bet  = (const float*)d_in[8];
    const float* gam2 = (const float*)d_in[9];
    const float* bet2 = (const float*)d_in[10];
    const float* bnw  = (const float*)d_in[11];

    char* ws = (char*)d_ws;
    short* a   = (short*)ws;                    // 8 MB attention output (bf16)
    short* qws = (short*)(ws + (8 << 20));      // 8 MB fragment-ordered Q; reused as yab
    short* yab = qws;                           // alias: outproj writes after attn read qws
    short* kws = (short*)(ws + (16 << 20));     // 8 MB fragment-ordered K
    short* vws = (short*)(ws + (24 << 20));     // 8 MB fragment-ordered V
    float* pdef = (float*)(ws + (32 << 20));    // 4 MB fragment-ordered f32 pde*log2e
    short* wib = (short*)(ws + (36 << 20));     // 384 KB bf16 in_proj_w
    short* wob = (short*)(ws + (36 << 20) + (512 << 10));  // 128 KB bf16 out_w
    float* stats = (float*)(ws + (37 << 20));   // chsum[512] chsq[512] bsum[4096] params[1024]
    float* chsum = stats;
    float* chsq  = stats + 512;
    float* bsum  = stats + 1024;
    float* params = stats + 1024 + 4096;
    float* y = (float*)d_out;

    hipMemsetAsync(stats, 0, (512 + 512 + 4096) * sizeof(float), stream);
    k_prep<<<1280, 256, 0, stream>>>(wi, wo, pde, wib, wob, pdef);
    k_qkv<<<dim3(128, 3, 2), 256, 0, stream>>>(x, x2, wib, bi, qws, kws, vws);
    k_attn<<<2048, 256, 0, stream>>>(qws, kws, vws, pdef, a);
    k_outproj<<<dim3(128, 2, 2), 256, 0, stream>>>(a, wob, bo, yab, chsum, chsq, bsum);
    k_finalize<<<1, 256, 0, stream>>>(chsum, chsq, bsum, gam, bet, gam2, bet2, bnw,
                                      params, y + 4194304);
    k_affine<<<2048, 256, 0, stream>>>(yab, y, params);
}

// Round 18
// 137.881 us; speedup vs baseline: 1.0051x; 1.0051x over previous
//
#include <hip/hip_runtime.h>
#include <hip/hip_bf16.h>

#define B_ 8
#define S_ 1024
#define E_ 256
#define H_ 8
#define HD_ 32
#define SCALE_ 0.17677669529663687f   // 32^-0.5
#define LOG2E_ 1.44269504088896f
#define QSCALE_ (SCALE_ * LOG2E_)
#define EPS_ 1e-5f

typedef __attribute__((ext_vector_type(8))) short bf16x8;
typedef __attribute__((ext_vector_type(4))) short bf16x4;
typedef __attribute__((ext_vector_type(4))) float f32x4;

__device__ inline short f2bf(float f) {
    union { float f; unsigned u; } v; v.f = f;
    unsigned r = v.u + 0x7fff + ((v.u >> 16) & 1);
    return (short)(r >> 16);
}

// single-instruction 2xf32 -> packed bf16x2 (RTNE) — gfx950 v_cvt_pk_bf16_f32
__device__ inline unsigned cvtpk(float a, float b) {
    unsigned r;
    asm("v_cvt_pk_bf16_f32 %0, %1, %2" : "=v"(r) : "v"(a), "v"(b));
    return r;
}

__device__ inline float fexp2(float x) {
#if __has_builtin(__builtin_amdgcn_exp2f)
    return __builtin_amdgcn_exp2f(x);
#else
    return exp2f(x);
#endif
}

__device__ inline float bf2f(unsigned short s) {
    return __uint_as_float((unsigned)s << 16);
}

// XOR-swizzled LDS byte offset for a [64][256] bf16 tile (512B rows).
__device__ inline int swz(int row, int kbyte) {
    return row * 512 + (kbyte ^ ((row & 7) << 4));
}

// ---------------------------------------------------------------------------
// Kernel 0: one-shot conversions (weights + pde only; x converted in k_qkv).
//  wib [768][256]     bf16   <- in_proj_w
//  wob [256][256]     bf16   <- out_w
//  pdef[sb][tb][lane][4] f32 <- pde * log2e, fragment-ordered:
//        lane = ((t>>2)&3)*16 + (s&15), r = t&3
// ---------------------------------------------------------------------------
__global__ __launch_bounds__(256) void k_prep(
    const float* __restrict__ wi, const float* __restrict__ wo,
    const float* __restrict__ pde,
    short* __restrict__ wib, short* __restrict__ wob,
    float* __restrict__ pdef)
{
    const int NWI = 768 * 256 / 4;        // 49152
    const int NWO = 256 * 256 / 4;        // 16384
    const int NP  = 1024 * 1024 / 4;      // 262144
    const int total = NWI + NWO + NP;
    for (int q4 = blockIdx.x * 256 + threadIdx.x; q4 < total;
         q4 += gridDim.x * 256) {
        if (q4 < NWI) {
            long i = (long)q4 * 4;
            float4 v = *reinterpret_cast<const float4*>(wi + i);
            short4 s; s.x = f2bf(v.x); s.y = f2bf(v.y); s.z = f2bf(v.z); s.w = f2bf(v.w);
            *reinterpret_cast<short4*>(wib + i) = s;
        } else if (q4 < NWI + NWO) {
            long i = (long)(q4 - NWI) * 4;
            float4 v = *reinterpret_cast<const float4*>(wo + i);
            short4 s; s.x = f2bf(v.x); s.y = f2bf(v.y); s.z = f2bf(v.z); s.w = f2bf(v.w);
            *reinterpret_cast<short4*>(wob + i) = s;
        } else {
            long i = (long)(q4 - NWI - NWO) * 4;
            int s = (int)(i >> 10), t = (int)(i & 1023);
            float4 v = *reinterpret_cast<const float4*>(pde + i);
            int dest = (s >> 4) * 16384 + (t >> 4) * 256
                     + ((((t >> 2) & 3) << 4) | (s & 15)) * 4;
            float4* d = reinterpret_cast<float4*>(pdef + dest);
            float4 o; o.x = v.x * LOG2E_; o.y = v.y * LOG2E_;
            o.z = v.z * LOG2E_; o.w = v.w * LOG2E_;
            *d = o;
        }
    }
}

// ---------------------------------------------------------------------------
// Kernel 1: QKV projection.  qkv = x @ Wi^T + bi  (M=8192/input, N=768, K=256)
// A staged ONCE from f32 x (f2bf in staging); each block computes TWO
// consecutive n-tiles (grid.y = 6). Outputs fragment-ordered per (inp,b,h)
// group g (64KB each). Epilogue per n-tile via LDS Tb[64][72].
// [byte-identical to the R15/R16-verified version]
// ---------------------------------------------------------------------------
__global__ __launch_bounds__(256) void k_qkv(
    const float* __restrict__ x0, const float* __restrict__ x1,
    const short* __restrict__ wib, const float* __restrict__ bias,
    short* __restrict__ qws, short* __restrict__ kws, short* __restrict__ vws)
{
    __shared__ alignas(16) short lA[64 * 256];
    __shared__ alignas(16) short lB[64 * 256];
    __shared__ alignas(16) short Tb[64 * 72];
    const int m0 = blockIdx.x * 64;
    const int inp = blockIdx.z;
    const float* x = inp ? x1 : x0;
    const int tid = threadIdx.x;

    // ---- stage A once (f32 x -> bf16 swizzled LDS) ----
    #pragma unroll
    for (int i = 0; i < 16; ++i) {
        int fid = tid + 256 * i;
        int r = fid >> 6, c4 = fid & 63;
        float4 vv = *reinterpret_cast<const float4*>(x + (long)(m0 + r) * 256 + c4 * 4);
        short4 sv; sv.x = f2bf(vv.x); sv.y = f2bf(vv.y); sv.z = f2bf(vv.z); sv.w = f2bf(vv.w);
        *reinterpret_cast<short4*>(reinterpret_cast<char*>(lA) + swz(r, c4 * 8)) = sv;
    }

    const int wv = tid >> 6, ln = tid & 63;
    const int row16 = ln & 15, kg = ln >> 4;
    const int arow = wv * 16 + row16;
    const int b = m0 >> 10;
    const int sbb = (m0 & 1023) >> 4;         // base 16-row tile index

    for (int t = 0; t < 2; ++t) {
        const int n0 = (blockIdx.y * 2 + t) * 64;

        // ---- stage B for this n-tile ----
        #pragma unroll
        for (int i = 0; i < 8; ++i) {
            int fid = tid + 256 * i;
            int r = fid >> 5, c = fid & 31;
            int4 v = *reinterpret_cast<const int4*>(wib + (long)(n0 + r) * 256 + c * 8);
            *reinterpret_cast<int4*>(reinterpret_cast<char*>(lB) + swz(r, c * 16)) = v;
        }
        __syncthreads();    // A+B visible; also orders prev emit before Tb rewrite

        f32x4 acc[4] = {};
        #pragma unroll
        for (int kc = 0; kc < 8; ++kc) {
            int kbyte = kc * 64 + kg * 16;
            bf16x8 af = *reinterpret_cast<const bf16x8*>(
                reinterpret_cast<char*>(lA) + swz(arow, kbyte));
            #pragma unroll
            for (int n = 0; n < 4; ++n) {
                int brow = n * 16 + row16;
                bf16x8 bfg = *reinterpret_cast<const bf16x8*>(
                    reinterpret_cast<char*>(lB) + swz(brow, kbyte));
                acc[n] = __builtin_amdgcn_mfma_f32_16x16x32_bf16(af, bfg, acc[n], 0, 0, 0);
            }
        }

        // ---- epilogue: stage tile in Tb (bf16), then coalesced emit ----
        const int sect = n0 >> 8;             // 0=q 1=k 2=v
        #pragma unroll
        for (int n = 0; n < 4; ++n) {
            int o = n0 + n * 16 + row16;
            float bval = bias[o];
            #pragma unroll
            for (int r = 0; r < 4; ++r) {
                float val = acc[n][r] + bval;
                if (sect == 0) val *= QSCALE_;
                Tb[(wv * 16 + kg * 4 + r) * 72 + n * 16 + row16] = f2bf(val);
            }
        }
        __syncthreads();

        const int h0 = (n0 & 255) >> 5;       // base head (even)
        const long gi0 = (long)(inp * 64 + b * 8 + h0) * 32768;

        if (sect < 2) {
            short* dst = (sect == 0) ? qws : kws;
            #pragma unroll
            for (int i = 0; i < 2; ++i) {
                int uid = tid * 2 + i;        // 0..511
                int u = uid & 15;             // s16
                int chunk = uid >> 4;         // 0..31
                int oct = chunk & 3;
                int sb_loc = (chunk >> 2) & 3;
                int hh = chunk >> 4;          // 0..1
                int4 vv = *reinterpret_cast<const int4*>(
                    &Tb[(sb_loc * 16 + u) * 72 + hh * 32 + oct * 8]);
                long gi = gi0 + (long)hh * 32768;
                *reinterpret_cast<int4*>(
                    &dst[gi + (sbb + sb_loc) * 512 + oct * 128 + u * 8]) = vv;
            }
        } else {
            #pragma unroll
            for (int i = 0; i < 2; ++i) {
                int uid = tid * 2 + i;        // 0..511
                int u8 = uid & 7;             // unit within 64-short chunk
                int chunk = uid >> 3;         // 0..63
                int q4 = chunk & 3;
                int c = (chunk >> 2) & 1;
                int tb_loc = (chunk >> 3) & 3;
                int hh = chunk >> 5;          // 0..1
                int srow = tb_loc * 16 + q4 * 4;
                int col = hh * 32 + c * 16 + u8 * 2;
                unsigned p0 = *reinterpret_cast<const unsigned*>(&Tb[(srow + 0) * 72 + col]);
                unsigned p1 = *reinterpret_cast<const unsigned*>(&Tb[(srow + 1) * 72 + col]);
                unsigned p2 = *reinterpret_cast<const unsigned*>(&Tb[(srow + 2) * 72 + col]);
                unsigned p3 = *reinterpret_cast<const unsigned*>(&Tb[(srow + 3) * 72 + col]);
                int4 vv;
                vv.x = (int)((p0 & 0xffffu) | (p1 << 16));
                vv.y = (int)((p2 & 0xffffu) | (p3 << 16));
                vv.z = (int)((p0 >> 16) | (p1 & 0xffff0000u));
                vv.w = (int)((p2 >> 16) | (p3 & 0xffff0000u));
                long gi = gi0 + (long)hh * 32768;
                *reinterpret_cast<int4*>(
                    &vws[gi + (sbb + tb_loc) * 512 + c * 256 + q4 * 64 + u8 * 8]) = vv;
            }
        }
    }
}

// ---------------------------------------------------------------------------
// Kernel 2: flash attention, no online max. Swapped QK^T (A=K, B=Q, C=pdef
// f32 frag) -> lane owns q=lane&15, t=kg*4+r == A-frag of mfma 16x16x16, so
// PV consumes exp2'd scores with zero movement. Row-sum via a ones-MFMA into
// accs (same C layout as O accumulator -> denominator in-lane, no shfl).
// P pack via single-instruction v_cvt_pk_bf16_f32; exp via raw v_exp_f32.
// All loads fragment-ordered 1-segment. No LDS.  [byte-identical to R11]
// ---------------------------------------------------------------------------
__global__ __launch_bounds__(256) void k_attn(
    const short* __restrict__ qws, const short* __restrict__ kws,
    const short* __restrict__ vws, const float* __restrict__ pdef,
    short* __restrict__ aout)
{
    const int L = blockIdx.x;
    const int xcd = L & 7, kidx = L >> 3;
    const int qb = kidx >> 4;                 // 0..15
    const int g  = xcd * 16 + (kidx & 15);    // 0..127 = inp*64 + b*8 + h
    const int inp = g >> 6, bh = g & 63, b = bh >> 3, h = bh & 7;
    const int tid = threadIdx.x, wv = tid >> 6, ln = tid & 63;
    const int row16 = ln & 15, kg = ln >> 4;
    const long gbase = (long)g * 32768;
    const int sb = qb * 4 + wv;               // 16-row q-tile index (0..63)

    bf16x8 qf = *reinterpret_cast<const bf16x8*>(qws + gbase + sb * 512 + ln * 8);
    const short* kp = kws + gbase + ln * 8;
    const short* vp = vws + gbase + ln * 4;
    const float* pp = pdef + (long)sb * 16384 + ln * 4;

    union { unsigned u[2]; bf16x4 v; } ones;
    ones.u[0] = 0x3F803F80u; ones.u[1] = 0x3F803F80u;

    f32x4 acc0 = {}, acc1 = {}, accs = {};

    #pragma unroll 4
    for (int tb = 0; tb < 64; ++tb) {
        bf16x8 kf = *reinterpret_cast<const bf16x8*>(kp + tb * 512);
        f32x4 c = *reinterpret_cast<const f32x4*>(pp + tb * 256);
        f32x4 sv = __builtin_amdgcn_mfma_f32_16x16x32_bf16(kf, qf, c, 0, 0, 0);
        float p0 = fexp2(sv[0]), p1 = fexp2(sv[1]);
        float p2 = fexp2(sv[2]), p3 = fexp2(sv[3]);
        union { unsigned u[2]; bf16x4 v; } pa;
        pa.u[0] = cvtpk(p0, p1);
        pa.u[1] = cvtpk(p2, p3);
        bf16x4 v0 = *reinterpret_cast<const bf16x4*>(vp + tb * 512);
        bf16x4 v1 = *reinterpret_cast<const bf16x4*>(vp + tb * 512 + 256);
        acc0 = __builtin_amdgcn_mfma_f32_16x16x16bf16_1k(pa.v, v0, acc0, 0, 0, 0);
        acc1 = __builtin_amdgcn_mfma_f32_16x16x16bf16_1k(pa.v, v1, acc1, 0, 0, 0);
        accs = __builtin_amdgcn_mfma_f32_16x16x16bf16_1k(pa.v, ones.v, accs, 0, 0, 0);
    }

    // acc layout: O[q = kg*4+r][e = h*32 + c2*16 + row16]; accs[r] = rowsum(q)
    #pragma unroll
    for (int c2 = 0; c2 < 2; ++c2) {
        int e = h * 32 + c2 * 16 + row16;
        #pragma unroll
        for (int r = 0; r < 4; ++r) {
            int s = qb * 64 + wv * 16 + kg * 4 + r;
            float val = (c2 ? acc1[r] : acc0[r]) / accs[r];
            aout[((long)inp * 8192 + b * 1024 + s) * 256 + e] = f2bf(val);
        }
    }
}

// ---------------------------------------------------------------------------
// Kernel 3: out-proj GEMM + BN/MMD statistics.  Ya = a @ Wo^T + bo
// A-tile staged ONCE; each block computes TWO n-tiles (grid.y = 2).
// Writes Ya as bf16 into ws (yab); statistics accumulate from unrounded f32.
// ---------------------------------------------------------------------------
__global__ __launch_bounds__(256) void k_outproj(
    const short* __restrict__ a, const short* __restrict__ wob,
    const float* __restrict__ bias, short* __restrict__ yab,
    float* __restrict__ chsum, float* __restrict__ chsq,
    float* __restrict__ bsum)
{
    __shared__ alignas(16) short lA[64 * 256];
    __shared__ alignas(16) short lB[64 * 256];
    const int m0 = blockIdx.x * 64;
    const int inp = blockIdx.z;
    const int tid = threadIdx.x;
    const short* asrc = a + (long)inp * 8192 * 256;

    #pragma unroll
    for (int i = 0; i < 8; ++i) {
        int fid = tid + 256 * i;
        int r = fid >> 5, c = fid & 31;
        int4 v = *reinterpret_cast<const int4*>(asrc + (long)(m0 + r) * 256 + c * 8);
        *reinterpret_cast<int4*>(reinterpret_cast<char*>(lA) + swz(r, c * 16)) = v;
    }

    const int wv = tid >> 6, ln = tid & 63;
    const int row16 = ln & 15, kg = ln >> 4;
    const int arow = wv * 16 + row16;

    for (int t = 0; t < 2; ++t) {
        const int n0 = (blockIdx.y * 2 + t) * 64;
        #pragma unroll
        for (int i = 0; i < 8; ++i) {
            int fid = tid + 256 * i;
            int r = fid >> 5, c = fid & 31;
            int4 v = *reinterpret_cast<const int4*>(wob + (long)(n0 + r) * 256 + c * 8);
            *reinterpret_cast<int4*>(reinterpret_cast<char*>(lB) + swz(r, c * 16)) = v;
        }
        __syncthreads();    // A+B visible

        f32x4 acc[4] = {};
        #pragma unroll
        for (int kc = 0; kc < 8; ++kc) {
            int kbyte = kc * 64 + kg * 16;
            bf16x8 af = *reinterpret_cast<const bf16x8*>(
                reinterpret_cast<char*>(lA) + swz(arow, kbyte));
            #pragma unroll
            for (int n = 0; n < 4; ++n) {
                int brow = n * 16 + row16;
                bf16x8 bfg = *reinterpret_cast<const bf16x8*>(
                    reinterpret_cast<char*>(lB) + swz(brow, kbyte));
                acc[n] = __builtin_amdgcn_mfma_f32_16x16x32_bf16(af, bfg, acc[n], 0, 0, 0);
            }
        }
        #pragma unroll
        for (int n = 0; n < 4; ++n) {
            int o = n0 + n * 16 + row16;
            float bv = bias[o];
            float sum = 0.f, sq = 0.f;
            #pragma unroll
            for (int r = 0; r < 4; ++r) {
                long grow = m0 + wv * 16 + kg * 4 + r;
                float val = acc[n][r] + bv;
                yab[(long)inp * 2097152 + grow * 256 + o] = f2bf(val);
                sum += val; sq += val * val;
            }
            sum += __shfl_xor(sum, 16); sum += __shfl_xor(sum, 32);
            sq  += __shfl_xor(sq, 16);  sq  += __shfl_xor(sq, 32);
            if (kg == 0) {
                atomicAdd(&chsum[inp * 256 + o], sum);
                atomicAdd(&chsq[inp * 256 + o], sq);
                int b = m0 >> 10;
                atomicAdd(&bsum[(inp * 8 + b) * 256 + o], sum);
            }
        }
        __syncthreads();    // ensure MFMA reads of lB done before restage
    }
}

// ---------------------------------------------------------------------------
// Kernel 4 (1 block): BN stats -> affine params; per-(b,e) means -> MMD loss.
// Distance loop vectorized: tot stride 276 floats (16B-aligned rows) +
// float4 LDS reads (64 iters instead of 256 scalar).
// ---------------------------------------------------------------------------
__global__ __launch_bounds__(256) void k_finalize(
    const float* __restrict__ chsum, const float* __restrict__ chsq,
    const float* __restrict__ bsum, const float* __restrict__ gamma,
    const float* __restrict__ beta, const float* __restrict__ gamma2,
    const float* __restrict__ beta2, const float* __restrict__ bnw,
    float* __restrict__ params, float* __restrict__ loss_out)
{
    __shared__ float tot[16][276];
    __shared__ float red[8];
    const int tid = threadIdx.x;
    const float w = (1.f / (1.f + __expf(-bnw[0])) + 1.f) * 0.5f;
    const int e = tid;
    float m1 = chsum[e] * (1.f / 8192.f);
    float v1 = chsq[e] * (1.f / 8192.f) - m1 * m1;
    float m2 = chsum[256 + e] * (1.f / 8192.f);
    float v2 = chsq[256 + e] * (1.f / 8192.f) - m2 * m2;
    float mfa = w * m1 + (1.f - w) * m2, mfb = w * m2 + (1.f - w) * m1;
    float vfa = w * v1 + (1.f - w) * v2, vfb = w * v2 + (1.f - w) * v1;
    float sA = gamma[e] * rsqrtf(vfa + EPS_);
    float bA = beta[e] - sA * mfa;
    float sB = gamma2[e] * rsqrtf(vfb + EPS_);
    float bB = beta2[e] - sB * mfb;
    params[e] = sA; params[256 + e] = bA; params[512 + e] = sB; params[768 + e] = bB;
    #pragma unroll
    for (int b = 0; b < 8; ++b) {
        tot[b][e]     = sA * (bsum[b * 256 + e] * (1.f / 1024.f)) + bA;
        tot[8 + b][e] = sB * (bsum[(8 + b) * 256 + e] * (1.f / 1024.f)) + bB;
    }
    __syncthreads();
    const int i = tid >> 4, j = tid & 15;
    const float4* ri = reinterpret_cast<const float4*>(&tot[i][0]);
    const float4* rj = reinterpret_cast<const float4*>(&tot[j][0]);
    float d = 0.f;
    for (int ee = 0; ee < 64; ++ee) {
        float4 va = ri[ee], vb = rj[ee];
        float dx = va.x - vb.x, dy = va.y - vb.y;
        float dz = va.z - vb.z, dw = va.w - vb.w;
        d += (dx * dx + dy * dy) + (dz * dz + dw * dw);
    }
    float t = d;
    #pragma unroll
    for (int off = 1; off < 64; off <<= 1) t += __shfl_xor(t, off);
    if ((tid & 63) == 0) red[tid >> 6] = t;
    __syncthreads();
    float dsum = red[0] + red[1] + red[2] + red[3];
    float bw = dsum * (1.f / 240.f) * 0.25f;
    float kern = 0.f, bwi = bw;
    #pragma unroll
    for (int kkk = 0; kkk < 5; ++kkk) { kern += __expf(-d / bwi); bwi *= 2.f; }
    float c = (((i < 8) == (j < 8)) ? 1.f : -1.f) * kern;
    #pragma unroll
    for (int off = 1; off < 64; off <<= 1) c += __shfl_xor(c, off);
    if ((tid & 63) == 0) red[4 + (tid >> 6)] = c;
    __syncthreads();
    if (tid == 0) loss_out[0] = (red[4] + red[5] + red[6] + red[7]) * (1.f / 64.f);
}

// ---------------------------------------------------------------------------
// Kernel 5: affine from bf16 Ya -> f32 d_out (Y = sA*Ya + bA, Y2 = sB*Yb + bB)
// params staged in LDS once per block.
// ---------------------------------------------------------------------------
__global__ __launch_bounds__(256) void k_affine(
    const short* __restrict__ yab, float* __restrict__ y,
    const float* __restrict__ params)
{
    __shared__ float pl[1024];
    {
        float4 v = *reinterpret_cast<const float4*>(params + threadIdx.x * 4);
        *reinterpret_cast<float4*>(pl + threadIdx.x * 4) = v;
    }
    __syncthreads();
    const long total4 = 4194304 / 4;
    for (long idx4 = (long)blockIdx.x * 256 + threadIdx.x; idx4 < total4;
         idx4 += (long)gridDim.x * 256) {
        long idx = idx4 * 4;
        int inp = (int)((idx >> 21) & 1);
        int e = (int)(idx & 255);
        const float* sA = pl + inp * 512;
        const float* bA = sA + 256;
        short4 s = *reinterpret_cast<const short4*>(yab + idx);
        float4 v;
        v.x = bf2f((unsigned short)s.x);
        v.y = bf2f((unsigned short)s.y);
        v.z = bf2f((unsigned short)s.z);
        v.w = bf2f((unsigned short)s.w);
        v.x = sA[e] * v.x + bA[e];
        v.y = sA[e + 1] * v.y + bA[e + 1];
        v.z = sA[e + 2] * v.z + bA[e + 2];
        v.w = sA[e + 3] * v.w + bA[e + 3];
        *reinterpret_cast<float4*>(y + idx) = v;
    }
}

extern "C" void kernel_launch(void* const* d_in, const int* in_sizes, int n_in,
                              void* d_out, int out_size, void* d_ws, size_t ws_size,
                              hipStream_t stream) {
    (void)in_sizes; (void)n_in; (void)out_size; (void)ws_size;
    const float* x    = (const float*)d_in[0];
    const float* x2   = (const float*)d_in[1];
    const float* pde  = (const float*)d_in[2];
    const float* wi   = (const float*)d_in[3];
    const float* bi   = (const float*)d_in[4];
    const float* wo   = (const float*)d_in[5];
    const float* bo   = (const float*)d_in[6];
    const float* gam  = (const float*)d_in[7];
    const float* bet  = (const float*)d_in[8];
    const float* gam2 = (const float*)d_in[9];
    const float* bet2 = (const float*)d_in[10];
    const float* bnw  = (const float*)d_in[11];

    char* ws = (char*)d_ws;
    short* a   = (short*)ws;                    // 8 MB attention output (bf16)
    short* qws = (short*)(ws + (8 << 20));      // 8 MB fragment-ordered Q; reused as yab
    short* yab = qws;                           // alias: outproj writes after attn read qws
    short* kws = (short*)(ws + (16 << 20));     // 8 MB fragment-ordered K
    short* vws = (short*)(ws + (24 << 20));     // 8 MB fragment-ordered V
    float* pdef = (float*)(ws + (32 << 20));    // 4 MB fragment-ordered f32 pde*log2e
    short* wib = (short*)(ws + (36 << 20));     // 384 KB bf16 in_proj_w
    short* wob = (short*)(ws + (36 << 20) + (512 << 10));  // 128 KB bf16 out_w
    float* stats = (float*)(ws + (37 << 20));   // chsum[512] chsq[512] bsum[4096] params[1024]
    float* chsum = stats;
    float* chsq  = stats + 512;
    float* bsum  = stats + 1024;
    float* params = stats + 1024 + 4096;
    float* y = (float*)d_out;

    hipMemsetAsync(stats, 0, (512 + 512 + 4096) * sizeof(float), stream);
    k_prep<<<1280, 256, 0, stream>>>(wi, wo, pde, wib, wob, pdef);
    k_qkv<<<dim3(128, 6, 2), 256, 0, stream>>>(x, x2, wib, bi, qws, kws, vws);
    k_attn<<<2048, 256, 0, stream>>>(qws, kws, vws, pdef, a);
    k_outproj<<<dim3(128, 2, 2), 256, 0, stream>>>(a, wob, bo, yab, chsum, chsq, bsum);
    k_finalize<<<1, 256, 0, stream>>>(chsum, chsq, bsum, gam, bet, gam2, bet2, bnw,
                                      params, y + 4194304);
    k_affine<<<2048, 256, 0, stream>>>(yab, y, params);
}

// Round 19
// 137.180 us; speedup vs baseline: 1.0102x; 1.0051x over previous
//
#include <hip/hip_runtime.h>
#include <hip/hip_bf16.h>

#define B_ 8
#define S_ 1024
#define E_ 256
#define H_ 8
#define HD_ 32
#define SCALE_ 0.17677669529663687f   // 32^-0.5
#define LOG2E_ 1.44269504088896f
#define QSCALE_ (SCALE_ * LOG2E_)
#define EPS_ 1e-5f

typedef __attribute__((ext_vector_type(8))) short bf16x8;
typedef __attribute__((ext_vector_type(4))) short bf16x4;
typedef __attribute__((ext_vector_type(4))) float f32x4;

__device__ inline short f2bf(float f) {
    union { float f; unsigned u; } v; v.f = f;
    unsigned r = v.u + 0x7fff + ((v.u >> 16) & 1);
    return (short)(r >> 16);
}

// single-instruction 2xf32 -> packed bf16x2 (RTNE) — gfx950 v_cvt_pk_bf16_f32
__device__ inline unsigned cvtpk(float a, float b) {
    unsigned r;
    asm("v_cvt_pk_bf16_f32 %0, %1, %2" : "=v"(r) : "v"(a), "v"(b));
    return r;
}

__device__ inline float fexp2(float x) {
#if __has_builtin(__builtin_amdgcn_exp2f)
    return __builtin_amdgcn_exp2f(x);
#else
    return exp2f(x);
#endif
}

__device__ inline float bf2f(unsigned short s) {
    return __uint_as_float((unsigned)s << 16);
}

// XOR-swizzled LDS byte offset for a [64][256] bf16 tile (512B rows).
__device__ inline int swz(int row, int kbyte) {
    return row * 512 + (kbyte ^ ((row & 7) << 4));
}

// ---------------------------------------------------------------------------
// Kernel 0: one-shot conversions (weights + pde only; x converted in k_qkv).
//  wib [768][256]     bf16   <- in_proj_w
//  wob [256][256]     bf16   <- out_w
//  pdef[sb][tb][lane][4] f32 <- pde * log2e, fragment-ordered:
//        lane = ((t>>2)&3)*16 + (s&15), r = t&3
// ---------------------------------------------------------------------------
__global__ __launch_bounds__(256) void k_prep(
    const float* __restrict__ wi, const float* __restrict__ wo,
    const float* __restrict__ pde,
    short* __restrict__ wib, short* __restrict__ wob,
    float* __restrict__ pdef)
{
    const int NWI = 768 * 256 / 4;        // 49152
    const int NWO = 256 * 256 / 4;        // 16384
    const int NP  = 1024 * 1024 / 4;      // 262144
    const int total = NWI + NWO + NP;
    for (int q4 = blockIdx.x * 256 + threadIdx.x; q4 < total;
         q4 += gridDim.x * 256) {
        if (q4 < NWI) {
            long i = (long)q4 * 4;
            float4 v = *reinterpret_cast<const float4*>(wi + i);
            short4 s; s.x = f2bf(v.x); s.y = f2bf(v.y); s.z = f2bf(v.z); s.w = f2bf(v.w);
            *reinterpret_cast<short4*>(wib + i) = s;
        } else if (q4 < NWI + NWO) {
            long i = (long)(q4 - NWI) * 4;
            float4 v = *reinterpret_cast<const float4*>(wo + i);
            short4 s; s.x = f2bf(v.x); s.y = f2bf(v.y); s.z = f2bf(v.z); s.w = f2bf(v.w);
            *reinterpret_cast<short4*>(wob + i) = s;
        } else {
            long i = (long)(q4 - NWI - NWO) * 4;
            int s = (int)(i >> 10), t = (int)(i & 1023);
            float4 v = *reinterpret_cast<const float4*>(pde + i);
            int dest = (s >> 4) * 16384 + (t >> 4) * 256
                     + ((((t >> 2) & 3) << 4) | (s & 15)) * 4;
            float4* d = reinterpret_cast<float4*>(pdef + dest);
            float4 o; o.x = v.x * LOG2E_; o.y = v.y * LOG2E_;
            o.z = v.z * LOG2E_; o.w = v.w * LOG2E_;
            *d = o;
        }
    }
}

// ---------------------------------------------------------------------------
// Kernel 1: QKV projection.  qkv = x @ Wi^T + bi  (M=8192/input, N=768, K=256)
// A staged ONCE from f32 x (f2bf in staging); each block computes TWO
// consecutive n-tiles (grid.y = 6). Outputs fragment-ordered per (inp,b,h)
// group g (64KB each). Epilogue per n-tile via LDS Tb[64][72].
// ---------------------------------------------------------------------------
__global__ __launch_bounds__(256) void k_qkv(
    const float* __restrict__ x0, const float* __restrict__ x1,
    const short* __restrict__ wib, const float* __restrict__ bias,
    short* __restrict__ qws, short* __restrict__ kws, short* __restrict__ vws)
{
    __shared__ alignas(16) short lA[64 * 256];
    __shared__ alignas(16) short lB[64 * 256];
    __shared__ alignas(16) short Tb[64 * 72];
    const int m0 = blockIdx.x * 64;
    const int inp = blockIdx.z;
    const float* x = inp ? x1 : x0;
    const int tid = threadIdx.x;

    // ---- stage A once (f32 x -> bf16 swizzled LDS) ----
    #pragma unroll
    for (int i = 0; i < 16; ++i) {
        int fid = tid + 256 * i;
        int r = fid >> 6, c4 = fid & 63;
        float4 vv = *reinterpret_cast<const float4*>(x + (long)(m0 + r) * 256 + c4 * 4);
        short4 sv; sv.x = f2bf(vv.x); sv.y = f2bf(vv.y); sv.z = f2bf(vv.z); sv.w = f2bf(vv.w);
        *reinterpret_cast<short4*>(reinterpret_cast<char*>(lA) + swz(r, c4 * 8)) = sv;
    }

    const int wv = tid >> 6, ln = tid & 63;
    const int row16 = ln & 15, kg = ln >> 4;
    const int arow = wv * 16 + row16;
    const int b = m0 >> 10;
    const int sbb = (m0 & 1023) >> 4;         // base 16-row tile index

    for (int t = 0; t < 2; ++t) {
        const int n0 = (blockIdx.y * 2 + t) * 64;

        // ---- stage B for this n-tile ----
        #pragma unroll
        for (int i = 0; i < 8; ++i) {
            int fid = tid + 256 * i;
            int r = fid >> 5, c = fid & 31;
            int4 v = *reinterpret_cast<const int4*>(wib + (long)(n0 + r) * 256 + c * 8);
            *reinterpret_cast<int4*>(reinterpret_cast<char*>(lB) + swz(r, c * 16)) = v;
        }
        __syncthreads();    // A+B visible; also orders prev emit before Tb rewrite

        f32x4 acc[4] = {};
        #pragma unroll
        for (int kc = 0; kc < 8; ++kc) {
            int kbyte = kc * 64 + kg * 16;
            bf16x8 af = *reinterpret_cast<const bf16x8*>(
                reinterpret_cast<char*>(lA) + swz(arow, kbyte));
            #pragma unroll
            for (int n = 0; n < 4; ++n) {
                int brow = n * 16 + row16;
                bf16x8 bfg = *reinterpret_cast<const bf16x8*>(
                    reinterpret_cast<char*>(lB) + swz(brow, kbyte));
                acc[n] = __builtin_amdgcn_mfma_f32_16x16x32_bf16(af, bfg, acc[n], 0, 0, 0);
            }
        }

        // ---- epilogue: stage tile in Tb (bf16), then coalesced emit ----
        const int sect = n0 >> 8;             // 0=q 1=k 2=v
        #pragma unroll
        for (int n = 0; n < 4; ++n) {
            int o = n0 + n * 16 + row16;
            float bval = bias[o];
            #pragma unroll
            for (int r = 0; r < 4; ++r) {
                float val = acc[n][r] + bval;
                if (sect == 0) val *= QSCALE_;
                Tb[(wv * 16 + kg * 4 + r) * 72 + n * 16 + row16] = f2bf(val);
            }
        }
        __syncthreads();

        const int h0 = (n0 & 255) >> 5;       // base head (even)
        const long gi0 = (long)(inp * 64 + b * 8 + h0) * 32768;

        if (sect < 2) {
            short* dst = (sect == 0) ? qws : kws;
            #pragma unroll
            for (int i = 0; i < 2; ++i) {
                int uid = tid * 2 + i;        // 0..511
                int u = uid & 15;             // s16
                int chunk = uid >> 4;         // 0..31
                int oct = chunk & 3;
                int sb_loc = (chunk >> 2) & 3;
                int hh = chunk >> 4;          // 0..1
                int4 vv = *reinterpret_cast<const int4*>(
                    &Tb[(sb_loc * 16 + u) * 72 + hh * 32 + oct * 8]);
                long gi = gi0 + (long)hh * 32768;
                *reinterpret_cast<int4*>(
                    &dst[gi + (sbb + sb_loc) * 512 + oct * 128 + u * 8]) = vv;
            }
        } else {
            #pragma unroll
            for (int i = 0; i < 2; ++i) {
                int uid = tid * 2 + i;        // 0..511
                int u8 = uid & 7;             // unit within 64-short chunk
                int chunk = uid >> 3;         // 0..63
                int q4 = chunk & 3;
                int c = (chunk >> 2) & 1;
                int tb_loc = (chunk >> 3) & 3;
                int hh = chunk >> 5;          // 0..1
                int srow = tb_loc * 16 + q4 * 4;
                int col = hh * 32 + c * 16 + u8 * 2;
                unsigned p0 = *reinterpret_cast<const unsigned*>(&Tb[(srow + 0) * 72 + col]);
                unsigned p1 = *reinterpret_cast<const unsigned*>(&Tb[(srow + 1) * 72 + col]);
                unsigned p2 = *reinterpret_cast<const unsigned*>(&Tb[(srow + 2) * 72 + col]);
                unsigned p3 = *reinterpret_cast<const unsigned*>(&Tb[(srow + 3) * 72 + col]);
                int4 vv;
                vv.x = (int)((p0 & 0xffffu) | (p1 << 16));
                vv.y = (int)((p2 & 0xffffu) | (p3 << 16));
                vv.z = (int)((p0 >> 16) | (p1 & 0xffff0000u));
                vv.w = (int)((p2 >> 16) | (p3 & 0xffff0000u));
                long gi = gi0 + (long)hh * 32768;
                *reinterpret_cast<int4*>(
                    &vws[gi + (sbb + tb_loc) * 512 + c * 256 + q4 * 64 + u8 * 8]) = vv;
            }
        }
    }
}

// ---------------------------------------------------------------------------
// Kernel 2: flash attention, no online max. Swapped QK^T (A=K, B=Q, C=pdef
// f32 frag) -> lane owns q=lane&15, t=kg*4+r == A-frag of mfma 16x16x16, so
// PV consumes exp2'd scores with zero movement. Row-sum via a ones-MFMA into
// accs (same C layout as O accumulator -> denominator in-lane, no shfl).
// P pack via single-instruction v_cvt_pk_bf16_f32; exp via raw v_exp_f32.
// All loads fragment-ordered 1-segment. No LDS.  [byte-identical to R11]
// ---------------------------------------------------------------------------
__global__ __launch_bounds__(256) void k_attn(
    const short* __restrict__ qws, const short* __restrict__ kws,
    const short* __restrict__ vws, const float* __restrict__ pdef,
    short* __restrict__ aout)
{
    const int L = blockIdx.x;
    const int xcd = L & 7, kidx = L >> 3;
    const int qb = kidx >> 4;                 // 0..15
    const int g  = xcd * 16 + (kidx & 15);    // 0..127 = inp*64 + b*8 + h
    const int inp = g >> 6, bh = g & 63, b = bh >> 3, h = bh & 7;
    const int tid = threadIdx.x, wv = tid >> 6, ln = tid & 63;
    const int row16 = ln & 15, kg = ln >> 4;
    const long gbase = (long)g * 32768;
    const int sb = qb * 4 + wv;               // 16-row q-tile index (0..63)

    bf16x8 qf = *reinterpret_cast<const bf16x8*>(qws + gbase + sb * 512 + ln * 8);
    const short* kp = kws + gbase + ln * 8;
    const short* vp = vws + gbase + ln * 4;
    const float* pp = pdef + (long)sb * 16384 + ln * 4;

    union { unsigned u[2]; bf16x4 v; } ones;
    ones.u[0] = 0x3F803F80u; ones.u[1] = 0x3F803F80u;

    f32x4 acc0 = {}, acc1 = {}, accs = {};

    #pragma unroll 4
    for (int tb = 0; tb < 64; ++tb) {
        bf16x8 kf = *reinterpret_cast<const bf16x8*>(kp + tb * 512);
        f32x4 c = *reinterpret_cast<const f32x4*>(pp + tb * 256);
        f32x4 sv = __builtin_amdgcn_mfma_f32_16x16x32_bf16(kf, qf, c, 0, 0, 0);
        float p0 = fexp2(sv[0]), p1 = fexp2(sv[1]);
        float p2 = fexp2(sv[2]), p3 = fexp2(sv[3]);
        union { unsigned u[2]; bf16x4 v; } pa;
        pa.u[0] = cvtpk(p0, p1);
        pa.u[1] = cvtpk(p2, p3);
        bf16x4 v0 = *reinterpret_cast<const bf16x4*>(vp + tb * 512);
        bf16x4 v1 = *reinterpret_cast<const bf16x4*>(vp + tb * 512 + 256);
        acc0 = __builtin_amdgcn_mfma_f32_16x16x16bf16_1k(pa.v, v0, acc0, 0, 0, 0);
        acc1 = __builtin_amdgcn_mfma_f32_16x16x16bf16_1k(pa.v, v1, acc1, 0, 0, 0);
        accs = __builtin_amdgcn_mfma_f32_16x16x16bf16_1k(pa.v, ones.v, accs, 0, 0, 0);
    }

    // acc layout: O[q = kg*4+r][e = h*32 + c2*16 + row16]; accs[r] = rowsum(q)
    #pragma unroll
    for (int c2 = 0; c2 < 2; ++c2) {
        int e = h * 32 + c2 * 16 + row16;
        #pragma unroll
        for (int r = 0; r < 4; ++r) {
            int s = qb * 64 + wv * 16 + kg * 4 + r;
            float val = (c2 ? acc1[r] : acc0[r]) / accs[r];
            aout[((long)inp * 8192 + b * 1024 + s) * 256 + e] = f2bf(val);
        }
    }
}

// ---------------------------------------------------------------------------
// Kernel 3: out-proj GEMM + BN/MMD statistics.  Ya = a @ Wo^T + bo
// A-tile staged ONCE; each block computes TWO n-tiles (grid.y = 2).
// Writes Ya as bf16 into ws (yab); statistics accumulate from unrounded f32.
// ---------------------------------------------------------------------------
__global__ __launch_bounds__(256) void k_outproj(
    const short* __restrict__ a, const short* __restrict__ wob,
    const float* __restrict__ bias, short* __restrict__ yab,
    float* __restrict__ chsum, float* __restrict__ chsq,
    float* __restrict__ bsum)
{
    __shared__ alignas(16) short lA[64 * 256];
    __shared__ alignas(16) short lB[64 * 256];
    const int m0 = blockIdx.x * 64;
    const int inp = blockIdx.z;
    const int tid = threadIdx.x;
    const short* asrc = a + (long)inp * 8192 * 256;

    #pragma unroll
    for (int i = 0; i < 8; ++i) {
        int fid = tid + 256 * i;
        int r = fid >> 5, c = fid & 31;
        int4 v = *reinterpret_cast<const int4*>(asrc + (long)(m0 + r) * 256 + c * 8);
        *reinterpret_cast<int4*>(reinterpret_cast<char*>(lA) + swz(r, c * 16)) = v;
    }

    const int wv = tid >> 6, ln = tid & 63;
    const int row16 = ln & 15, kg = ln >> 4;
    const int arow = wv * 16 + row16;

    for (int t = 0; t < 2; ++t) {
        const int n0 = (blockIdx.y * 2 + t) * 64;
        #pragma unroll
        for (int i = 0; i < 8; ++i) {
            int fid = tid + 256 * i;
            int r = fid >> 5, c = fid & 31;
            int4 v = *reinterpret_cast<const int4*>(wob + (long)(n0 + r) * 256 + c * 8);
            *reinterpret_cast<int4*>(reinterpret_cast<char*>(lB) + swz(r, c * 16)) = v;
        }
        __syncthreads();    // A+B visible

        f32x4 acc[4] = {};
        #pragma unroll
        for (int kc = 0; kc < 8; ++kc) {
            int kbyte = kc * 64 + kg * 16;
            bf16x8 af = *reinterpret_cast<const bf16x8*>(
                reinterpret_cast<char*>(lA) + swz(arow, kbyte));
            #pragma unroll
            for (int n = 0; n < 4; ++n) {
                int brow = n * 16 + row16;
                bf16x8 bfg = *reinterpret_cast<const bf16x8*>(
                    reinterpret_cast<char*>(lB) + swz(brow, kbyte));
                acc[n] = __builtin_amdgcn_mfma_f32_16x16x32_bf16(af, bfg, acc[n], 0, 0, 0);
            }
        }
        #pragma unroll
        for (int n = 0; n < 4; ++n) {
            int o = n0 + n * 16 + row16;
            float bv = bias[o];
            float sum = 0.f, sq = 0.f;
            #pragma unroll
            for (int r = 0; r < 4; ++r) {
                long grow = m0 + wv * 16 + kg * 4 + r;
                float val = acc[n][r] + bv;
                yab[(long)inp * 2097152 + grow * 256 + o] = f2bf(val);
                sum += val; sq += val * val;
            }
            sum += __shfl_xor(sum, 16); sum += __shfl_xor(sum, 32);
            sq  += __shfl_xor(sq, 16);  sq  += __shfl_xor(sq, 32);
            if (kg == 0) {
                atomicAdd(&chsum[inp * 256 + o], sum);
                atomicAdd(&chsq[inp * 256 + o], sq);
                int b = m0 >> 10;
                atomicAdd(&bsum[(inp * 8 + b) * 256 + o], sum);
            }
        }
        __syncthreads();    // ensure MFMA reads of lB done before restage
    }
}

// ---------------------------------------------------------------------------
// Kernel 4 (1 block): BN stats -> affine params; per-(b,e) means -> MMD loss.
// ---------------------------------------------------------------------------
__global__ __launch_bounds__(256) void k_finalize(
    const float* __restrict__ chsum, const float* __restrict__ chsq,
    const float* __restrict__ bsum, const float* __restrict__ gamma,
    const float* __restrict__ beta, const float* __restrict__ gamma2,
    const float* __restrict__ beta2, const float* __restrict__ bnw,
    float* __restrict__ params, float* __restrict__ loss_out)
{
    __shared__ float tot[16][257];
    __shared__ float red[8];
    const int tid = threadIdx.x;
    const float w = (1.f / (1.f + __expf(-bnw[0])) + 1.f) * 0.5f;
    const int e = tid;
    float m1 = chsum[e] * (1.f / 8192.f);
    float v1 = chsq[e] * (1.f / 8192.f) - m1 * m1;
    float m2 = chsum[256 + e] * (1.f / 8192.f);
    float v2 = chsq[256 + e] * (1.f / 8192.f) - m2 * m2;
    float mfa = w * m1 + (1.f - w) * m2, mfb = w * m2 + (1.f - w) * m1;
    float vfa = w * v1 + (1.f - w) * v2, vfb = w * v2 + (1.f - w) * v1;
    float sA = gamma[e] * rsqrtf(vfa + EPS_);
    float bA = beta[e] - sA * mfa;
    float sB = gamma2[e] * rsqrtf(vfb + EPS_);
    float bB = beta2[e] - sB * mfb;
    params[e] = sA; params[256 + e] = bA; params[512 + e] = sB; params[768 + e] = bB;
    #pragma unroll
    for (int b = 0; b < 8; ++b) {
        tot[b][e]     = sA * (bsum[b * 256 + e] * (1.f / 1024.f)) + bA;
        tot[8 + b][e] = sB * (bsum[(8 + b) * 256 + e] * (1.f / 1024.f)) + bB;
    }
    __syncthreads();
    const int i = tid >> 4, j = tid & 15;
    float d = 0.f;
    for (int ee = 0; ee < 256; ++ee) {
        float df = tot[i][ee] - tot[j][ee];
        d += df * df;
    }
    float t = d;
    #pragma unroll
    for (int off = 1; off < 64; off <<= 1) t += __shfl_xor(t, off);
    if ((tid & 63) == 0) red[tid >> 6] = t;
    __syncthreads();
    float dsum = red[0] + red[1] + red[2] + red[3];
    float bw = dsum * (1.f / 240.f) * 0.25f;
    float kern = 0.f, bwi = bw;
    #pragma unroll
    for (int kkk = 0; kkk < 5; ++kkk) { kern += __expf(-d / bwi); bwi *= 2.f; }
    float c = (((i < 8) == (j < 8)) ? 1.f : -1.f) * kern;
    #pragma unroll
    for (int off = 1; off < 64; off <<= 1) c += __shfl_xor(c, off);
    if ((tid & 63) == 0) red[4 + (tid >> 6)] = c;
    __syncthreads();
    if (tid == 0) loss_out[0] = (red[4] + red[5] + red[6] + red[7]) * (1.f / 64.f);
}

// ---------------------------------------------------------------------------
// Kernel 5: affine from bf16 Ya -> f32 d_out (Y = sA*Ya + bA, Y2 = sB*Yb + bB)
// params staged in LDS once per block.
// ---------------------------------------------------------------------------
__global__ __launch_bounds__(256) void k_affine(
    const short* __restrict__ yab, float* __restrict__ y,
    const float* __restrict__ params)
{
    __shared__ float pl[1024];
    {
        float4 v = *reinterpret_cast<const float4*>(params + threadIdx.x * 4);
        *reinterpret_cast<float4*>(pl + threadIdx.x * 4) = v;
    }
    __syncthreads();
    const long total4 = 4194304 / 4;
    for (long idx4 = (long)blockIdx.x * 256 + threadIdx.x; idx4 < total4;
         idx4 += (long)gridDim.x * 256) {
        long idx = idx4 * 4;
        int inp = (int)((idx >> 21) & 1);
        int e = (int)(idx & 255);
        const float* sA = pl + inp * 512;
        const float* bA = sA + 256;
        short4 s = *reinterpret_cast<const short4*>(yab + idx);
        float4 v;
        v.x = bf2f((unsigned short)s.x);
        v.y = bf2f((unsigned short)s.y);
        v.z = bf2f((unsigned short)s.z);
        v.w = bf2f((unsigned short)s.w);
        v.x = sA[e] * v.x + bA[e];
        v.y = sA[e + 1] * v.y + bA[e + 1];
        v.z = sA[e + 2] * v.z + bA[e + 2];
        v.w = sA[e + 3] * v.w + bA[e + 3];
        *reinterpret_cast<float4*>(y + idx) = v;
    }
}

extern "C" void kernel_launch(void* const* d_in, const int* in_sizes, int n_in,
                              void* d_out, int out_size, void* d_ws, size_t ws_size,
                              hipStream_t stream) {
    (void)in_sizes; (void)n_in; (void)out_size; (void)ws_size;
    const float* x    = (const float*)d_in[0];
    const float* x2   = (const float*)d_in[1];
    const float* pde  = (const float*)d_in[2];
    const float* wi   = (const float*)d_in[3];
    const float* bi   = (const float*)d_in[4];
    const float* wo   = (const float*)d_in[5];
    const float* bo   = (const float*)d_in[6];
    const float* gam  = (const float*)d_in[7];
    const float* bet  = (const float*)d_in[8];
    const float* gam2 = (const float*)d_in[9];
    const float* bet2 = (const float*)d_in[10];
    const float* bnw  = (const float*)d_in[11];

    char* ws = (char*)d_ws;
    short* a   = (short*)ws;                    // 8 MB attention output (bf16)
    short* qws = (short*)(ws + (8 << 20));      // 8 MB fragment-ordered Q; reused as yab
    short* yab = qws;                           // alias: outproj writes after attn read qws
    short* kws = (short*)(ws + (16 << 20));     // 8 MB fragment-ordered K
    short* vws = (short*)(ws + (24 << 20));     // 8 MB fragment-ordered V
    float* pdef = (float*)(ws + (32 << 20));    // 4 MB fragment-ordered f32 pde*log2e
    short* wib = (short*)(ws + (36 << 20));     // 384 KB bf16 in_proj_w
    short* wob = (short*)(ws + (36 << 20) + (512 << 10));  // 128 KB bf16 out_w
    float* stats = (float*)(ws + (37 << 20));   // chsum[512] chsq[512] bsum[4096] params[1024]
    float* chsum = stats;
    float* chsq  = stats + 512;
    float* bsum  = stats + 1024;
    float* params = stats + 1024 + 4096;
    float* y = (float*)d_out;

    hipMemsetAsync(stats, 0, (512 + 512 + 4096) * sizeof(float), stream);
    k_prep<<<1280, 256, 0, stream>>>(wi, wo, pde, wib, wob, pdef);
    k_qkv<<<dim3(128, 6, 2), 256, 0, stream>>>(x, x2, wib, bi, qws, kws, vws);
    k_attn<<<2048, 256, 0, stream>>>(qws, kws, vws, pdef, a);
    k_outproj<<<dim3(128, 2, 2), 256, 0, stream>>>(a, wob, bo, yab, chsum, chsq, bsum);
    k_finalize<<<1, 256, 0, stream>>>(chsum, chsq, bsum, gam, bet, gam2, bet2, bnw,
                                      params, y + 4194304);
    k_affine<<<2048, 256, 0, stream>>>(yab, y, params);
}